// Round 1
// baseline (410.484 us; speedup 1.0000x reference)
//
#include <hip/hip_runtime.h>

#define DEVINL __device__ __forceinline__

// Problem constants
#define BB 4
#define SS 4096
#define HIDD 1024
#define HH 16
#define DH 64
#define NQKV 3072
#define MM (BB * SS)  // 16384

typedef __attribute__((ext_vector_type(8))) short bf16x8_t;
typedef __attribute__((ext_vector_type(4))) float f32x4_t;

DEVINL float bf2f(ushort u) {
  union { unsigned int i; float f; } v;
  v.i = ((unsigned int)u) << 16;
  return v.f;
}
DEVINL ushort f2bf(float f) {
  unsigned int u = __float_as_uint(f);
  u = (u + 0x7fffu + ((u >> 16) & 1u)) >> 16;
  return (ushort)u;
}

// ---------------- fp32 -> bf16 convert (4 elems/thread) ----------------
__global__ __launch_bounds__(256) void k_f2bf(const float* __restrict__ src,
                                              ushort* __restrict__ dst, int n4) {
  int i = blockIdx.x * 256 + threadIdx.x;
  if (i >= n4) return;
  float4 v = ((const float4*)src)[i];
  ushort4 o;
  o.x = f2bf(v.x); o.y = f2bf(v.y); o.z = f2bf(v.z); o.w = f2bf(v.w);
  ((ushort4*)dst)[i] = o;
}

// ---------------- bf16 GEMM: C[M,N] = A[M,K] * B[N,K]^T + bias ----------------
// 128x128 tile, BK=64, 4 waves (2x2), each wave 4x4 frags of 16x16x32 MFMA.
// LDS XOR-swizzle (T2): 16B chunk index ^= (row & 7).
template <int STORE_F32>
__global__ __launch_bounds__(256) void k_gemm_bt(
    const ushort* __restrict__ A, const ushort* __restrict__ B,
    const float* __restrict__ bias, void* __restrict__ Cv,
    int M, int N, int K) {
  __shared__ ushort As[128 * 64];
  __shared__ ushort Bs[128 * 64];
  const int t = threadIdx.x;
  const int m0 = blockIdx.x * 128, n0 = blockIdx.y * 128;
  const int lane = t & 63, wave = t >> 6;
  const int wm = wave >> 1, wn = wave & 1;
  const int fr = lane & 15, g = lane >> 4;
  f32x4_t acc[4][4] = {};
  for (int k0 = 0; k0 < K; k0 += 64) {
#pragma unroll
    for (int i = 0; i < 4; ++i) {
      int id = i * 256 + t;
      int r = id >> 3, c = id & 7;
      int4 va = *(const int4*)&A[(size_t)(m0 + r) * K + k0 + c * 8];
      int4 vb = *(const int4*)&B[(size_t)(n0 + r) * K + k0 + c * 8];
      int cs = (c ^ (r & 7)) * 8;
      *(int4*)&As[r * 64 + cs] = va;
      *(int4*)&Bs[r * 64 + cs] = vb;
    }
    __syncthreads();
#pragma unroll
    for (int kk = 0; kk < 2; ++kk) {
      bf16x8_t af[4], bfg[4];
#pragma unroll
      for (int mi = 0; mi < 4; ++mi) {
        int r = wm * 64 + mi * 16 + fr;
        af[mi] = *(const bf16x8_t*)&As[r * 64 + (((kk * 4 + g) ^ (r & 7)) * 8)];
      }
#pragma unroll
      for (int ni = 0; ni < 4; ++ni) {
        int r = wn * 64 + ni * 16 + fr;
        bfg[ni] = *(const bf16x8_t*)&Bs[r * 64 + (((kk * 4 + g) ^ (r & 7)) * 8)];
      }
#pragma unroll
      for (int mi = 0; mi < 4; ++mi)
#pragma unroll
        for (int ni = 0; ni < 4; ++ni)
          acc[mi][ni] = __builtin_amdgcn_mfma_f32_16x16x32_bf16(
              af[mi], bfg[ni], acc[mi][ni], 0, 0, 0);
    }
    __syncthreads();
  }
// epilogue: D col = lane&15, row = (lane>>4)*4 + reg (HW-verified mapping)
#pragma unroll
  for (int ni = 0; ni < 4; ++ni) {
    int col = n0 + wn * 64 + ni * 16 + fr;
    float bv = bias[col];
#pragma unroll
    for (int mi = 0; mi < 4; ++mi) {
      int row = m0 + wm * 64 + mi * 16 + g * 4;
#pragma unroll
      for (int j = 0; j < 4; ++j) {
        float v = acc[mi][ni][j] + bv;
        if (STORE_F32)
          ((float*)Cv)[(size_t)(row + j) * N + col] = v;
        else
          ((ushort*)Cv)[(size_t)(row + j) * N + col] = f2bf(v);
      }
    }
  }
}

// ---------------- norms: partial sum of squares over s (per b,h,d) ----------------
// grid 256: block = bh*4 + part; part covers 1024 s values.
__global__ __launch_bounds__(256) void k_norms_part(const ushort* __restrict__ qkv,
                                                    float* __restrict__ part) {
  int bh = blockIdx.x >> 2, p = blockIdx.x & 3;
  int b = bh >> 4, h = bh & 15;
  int t = threadIdx.x;
  int d = t & 63, sg = t >> 6;
  const ushort* base = qkv + (size_t)(b * SS + p * 1024) * NQKV + h * 64 + d;
  float sq = 0.f, sk = 0.f;
  for (int s = sg; s < 1024; s += 4) {
    float q = bf2f(base[(size_t)s * NQKV]);
    float k = bf2f(base[(size_t)s * NQKV + HIDD]);
    sq += q * q;
    sk += k * k;
  }
  __shared__ float red[512];
  red[t] = sq;
  red[256 + t] = sk;
  __syncthreads();
  if (t < 64) {
    sq = red[t] + red[t + 64] + red[t + 128] + red[t + 192];
    sk = red[256 + t] + red[256 + t + 64] + red[256 + t + 128] + red[256 + t + 192];
    part[((size_t)(bh * 4 + p) * 2 + 0) * 64 + d] = sq;
    part[((size_t)(bh * 4 + p) * 2 + 1) * 64 + d] = sk;
  }
}

__global__ __launch_bounds__(256) void k_norms_fin(const float* __restrict__ part,
                                                   float* __restrict__ invq,
                                                   float* __restrict__ invk) {
  int idx = blockIdx.x * 256 + threadIdx.x;  // 4096 = bh*64 + d
  if (idx >= BB * HH * 64) return;
  int bh = idx >> 6, d = idx & 63;
  float sq = 0.f, sk = 0.f;
#pragma unroll
  for (int p = 0; p < 4; ++p) {
    sq += part[((size_t)(bh * 4 + p) * 2 + 0) * 64 + d];
    sk += part[((size_t)(bh * 4 + p) * 2 + 1) * 64 + d];
  }
  invq[idx] = 1.0f / fmaxf(sqrtf(sq), 1e-12f);
  invk[idx] = 1.0f / fmaxf(sqrtf(sk), 1e-12f);
}

// ---------------- gram partial: Wpart[bh][p][64][64] = sum_{s in part} Q[d,s]K[e,s] ----------------
__global__ __launch_bounds__(256) void k_gram_part(const ushort* __restrict__ qkv,
                                                   float* __restrict__ Wpart) {
  int bh = blockIdx.x, p = blockIdx.y;
  int b = bh >> 4, h = bh & 15;
  __shared__ float Qs[64][68];
  __shared__ float Ks[64][68];
  int t = threadIdx.x;
  int td = t & 15, te = t >> 4;
  float acc[4][4] = {};
  const ushort* qbase = qkv + (size_t)(b * SS + p * 1024) * NQKV + h * 64;
  for (int s0 = 0; s0 < 1024; s0 += 64) {
#pragma unroll
    for (int i = 0; i < 2; ++i) {
      int id = i * 256 + t;  // 512 units of 8 bf16
      int sr = id >> 3, c = id & 7;
      const ushort* ptr = qbase + (size_t)(s0 + sr) * NQKV + c * 8;
      int4 vq = *(const int4*)ptr;
      int4 vk = *(const int4*)(ptr + HIDD);
      const ushort* uq = (const ushort*)&vq;
      const ushort* uk = (const ushort*)&vk;
      float4 qlo = {bf2f(uq[0]), bf2f(uq[1]), bf2f(uq[2]), bf2f(uq[3])};
      float4 qhi = {bf2f(uq[4]), bf2f(uq[5]), bf2f(uq[6]), bf2f(uq[7])};
      float4 klo = {bf2f(uk[0]), bf2f(uk[1]), bf2f(uk[2]), bf2f(uk[3])};
      float4 khi = {bf2f(uk[4]), bf2f(uk[5]), bf2f(uk[6]), bf2f(uk[7])};
      *(float4*)&Qs[sr][c * 8] = qlo;
      *(float4*)&Qs[sr][c * 8 + 4] = qhi;
      *(float4*)&Ks[sr][c * 8] = klo;
      *(float4*)&Ks[sr][c * 8 + 4] = khi;
    }
    __syncthreads();
#pragma unroll 4
    for (int s = 0; s < 64; ++s) {
      float4 q = *(const float4*)&Qs[s][td * 4];
      float4 k = *(const float4*)&Ks[s][te * 4];
      const float qa[4] = {q.x, q.y, q.z, q.w};
      const float ka[4] = {k.x, k.y, k.z, k.w};
#pragma unroll
      for (int i = 0; i < 4; ++i)
#pragma unroll
        for (int j = 0; j < 4; ++j) acc[i][j] += qa[i] * ka[j];
    }
    __syncthreads();
  }
  float* wp = Wpart + (size_t)(bh * 4 + p) * 4096;
#pragma unroll
  for (int i = 0; i < 4; ++i)
#pragma unroll
    for (int j = 0; j < 4; ++j) wp[(td * 4 + i) * 64 + te * 4 + j] = acc[i][j];
}

// ---------------- fused scale + softmax + PV ----------------
// block (bh, p): rebuild W from partials, scale by invq*invk*temp/32, softmax rows,
// then out[d,s] = sum_e attn[d][e] V[e,s] over this block's s-quarter.
__global__ __launch_bounds__(256) void k_pv(const ushort* __restrict__ qkv,
                                            const float* __restrict__ Wpart,
                                            const float* __restrict__ invq,
                                            const float* __restrict__ invk,
                                            const float* __restrict__ temperature,
                                            ushort* __restrict__ attnout) {
  int bh = blockIdx.x, p = blockIdx.y;
  int b = bh >> 4, h = bh & 15;
  __shared__ float attn[64][65];
  __shared__ float Vs[64][68];
  int t = threadIdx.x;
  float tscale = temperature[h] * (1.0f / 32.0f);  // / sqrt(HID)
  for (int idx = t; idx < 4096; idx += 256) {
    int d = idx >> 6, e = idx & 63;
    float s = 0.f;
#pragma unroll
    for (int q = 0; q < 4; ++q) s += Wpart[(size_t)(bh * 4 + q) * 4096 + idx];
    attn[d][e] = s * invq[bh * 64 + d] * invk[bh * 64 + e] * tscale;
  }
  __syncthreads();
  if (t < 64) {
    float m = -1e30f;
#pragma unroll 8
    for (int e = 0; e < 64; ++e) m = fmaxf(m, attn[t][e]);
    float sum = 0.f;
#pragma unroll 8
    for (int e = 0; e < 64; ++e) {
      float v = __expf(attn[t][e] - m);
      attn[t][e] = v;
      sum += v;
    }
    float inv = 1.0f / sum;
#pragma unroll 8
    for (int e = 0; e < 64; ++e) attn[t][e] *= inv;
  }
  __syncthreads();
  int td = t & 15, ts = t >> 4;
  const ushort* vbase = qkv + (size_t)(b * SS + p * 1024) * NQKV + 2 * HIDD + h * 64;
  ushort* obase = attnout + (size_t)(b * SS + p * 1024) * HIDD + h * 64;
  for (int s0 = 0; s0 < 1024; s0 += 64) {
#pragma unroll
    for (int i = 0; i < 2; ++i) {
      int id = i * 256 + t;
      int sr = id >> 3, c = id & 7;
      int4 vv = *(const int4*)(vbase + (size_t)(s0 + sr) * NQKV + c * 8);
      const ushort* uv = (const ushort*)&vv;
      float4 lo = {bf2f(uv[0]), bf2f(uv[1]), bf2f(uv[2]), bf2f(uv[3])};
      float4 hi = {bf2f(uv[4]), bf2f(uv[5]), bf2f(uv[6]), bf2f(uv[7])};
      *(float4*)&Vs[sr][c * 8] = lo;
      *(float4*)&Vs[sr][c * 8 + 4] = hi;
    }
    __syncthreads();
    float acc[4][4] = {};  // [d][s]
#pragma unroll 4
    for (int e = 0; e < 64; ++e) {
      float a0 = attn[td * 4 + 0][e];
      float a1 = attn[td * 4 + 1][e];
      float a2 = attn[td * 4 + 2][e];
      float a3 = attn[td * 4 + 3][e];
      float v0 = Vs[ts * 4 + 0][e];
      float v1 = Vs[ts * 4 + 1][e];
      float v2 = Vs[ts * 4 + 2][e];
      float v3 = Vs[ts * 4 + 3][e];
      acc[0][0] += a0 * v0; acc[0][1] += a0 * v1; acc[0][2] += a0 * v2; acc[0][3] += a0 * v3;
      acc[1][0] += a1 * v0; acc[1][1] += a1 * v1; acc[1][2] += a1 * v2; acc[1][3] += a1 * v3;
      acc[2][0] += a2 * v0; acc[2][1] += a2 * v1; acc[2][2] += a2 * v2; acc[2][3] += a2 * v3;
      acc[3][0] += a3 * v0; acc[3][1] += a3 * v1; acc[3][2] += a3 * v2; acc[3][3] += a3 * v3;
    }
#pragma unroll
    for (int j = 0; j < 4; ++j) {
      ushort4 o;
      o.x = f2bf(acc[0][j]);
      o.y = f2bf(acc[1][j]);
      o.z = f2bf(acc[2][j]);
      o.w = f2bf(acc[3][j]);
      *(ushort4*)&obase[(size_t)(s0 + ts * 4 + j) * HIDD + td * 4] = o;
    }
    __syncthreads();
  }
}

extern "C" void kernel_launch(void* const* d_in, const int* in_sizes, int n_in,
                              void* d_out, int out_size, void* d_ws, size_t ws_size,
                              hipStream_t stream) {
  const float* x = (const float*)d_in[0];
  const float* Wqkv = (const float*)d_in[1];
  const float* bqkv = (const float*)d_in[2];
  const float* Wz = (const float*)d_in[3];
  const float* bz = (const float*)d_in[4];
  const float* temperature = (const float*)d_in[5];

  char* ws = (char*)d_ws;
  // layout (bytes):
  ushort* xb   = (ushort*)(ws + 0);           // 33,554,432  (aliased by attnout later)
  ushort* wqb  = (ushort*)(ws + 33554432);    // 6,291,456
  ushort* wzb  = (ushort*)(ws + 39845888);    // 2,097,152
  ushort* qkvb = (ushort*)(ws + 41943040);    // 100,663,296
  float* invq  = (float*)(ws + 142606336);    // 16,384
  float* invk  = (float*)(ws + 142622720);    // 16,384
  float* npart = (float*)(ws + 142639104);    // 131,072
  float* Wpart = (float*)(ws + 142770176);    // 4,194,304  (ends 146,964,480)
  ushort* attnout = xb;  // x is dead after QKV GEMM

  // 1) converts
  k_f2bf<<<dim3(16384), dim3(256), 0, stream>>>(x, xb, (MM * HIDD) / 4);
  k_f2bf<<<dim3(3072), dim3(256), 0, stream>>>(Wqkv, wqb, (NQKV * HIDD) / 4);
  k_f2bf<<<dim3(1024), dim3(256), 0, stream>>>(Wz, wzb, (HIDD * HIDD) / 4);

  // 2) QKV GEMM -> qkv bf16 [B,S,3072]
  k_gemm_bt<0><<<dim3(MM / 128, NQKV / 128), dim3(256), 0, stream>>>(
      xb, wqb, bqkv, (void*)qkvb, MM, NQKV, HIDD);

  // 3) norms
  k_norms_part<<<dim3(256), dim3(256), 0, stream>>>(qkvb, npart);
  k_norms_fin<<<dim3(16), dim3(256), 0, stream>>>(npart, invq, invk);

  // 4) gram partials, then fused softmax+PV
  k_gram_part<<<dim3(64, 4), dim3(256), 0, stream>>>(qkvb, Wpart);
  k_pv<<<dim3(64, 4), dim3(256), 0, stream>>>(qkvb, Wpart, invq, invk, temperature,
                                              attnout);

  // 5) output GEMM -> d_out fp32
  k_gemm_bt<1><<<dim3(MM / 128, HIDD / 128), dim3(256), 0, stream>>>(
      attnout, wzb, bz, d_out, MM, HIDD, HIDD);
}